// Round 13
// baseline (744.605 us; speedup 1.0000x reference)
//
#include <hip/hip_runtime.h>
#include <hip/hip_bf16.h>
#include <math.h>

#define EMB 512
#define HEADS 16
#define WS 8
#define BSZ 8
#define HW 64
#define NTOK (HW * HW)
#define WN 8
#define M_TOT (BSZ * NTOK)           // 32768
#define NELEM ((size_t)M_TOT * EMB)  // 16,777,216 per activation tensor

typedef _Float16 f16;
typedef _Float16 f16x4 __attribute__((ext_vector_type(4)));
typedef _Float16 f16x8 __attribute__((ext_vector_type(8)));
typedef float f32x4 __attribute__((ext_vector_type(4)));

__device__ inline f16x8 cvt8(float4 a, float4 b) {
  f16x8 h = {(f16)a.x, (f16)a.y, (f16)a.z, (f16)a.w,
             (f16)b.x, (f16)b.y, (f16)b.z, (f16)b.w};
  return h;
}

// ---------------------------------------------------------------------------
// weight conversion. z<4: permute rows to head-major (out row h*32+e comes
// from in row e*16+h) and permute bias; z>=4: identity copy.
// ---------------------------------------------------------------------------
struct CvtW { const float* w[6]; const float* b[4]; f16* out[6]; float* bp; };

__global__ __launch_bounds__(128) void cvt_w(CvtW P) {
  const int z = blockIdx.y;
  const int np = blockIdx.x;                       // output row 0..511
  const int src = (z < 4) ? ((np & 31) * 16 + (np >> 5)) : np;
  const float4* __restrict__ in = (const float4*)(P.w[z] + (size_t)src * 512);
  f16x4* __restrict__ out = (f16x4*)(P.out[z] + (size_t)np * 512);
  const int t = threadIdx.x;                       // 128 threads * 4 cols
  float4 v = in[t];
  f16x4 h = {(f16)v.x, (f16)v.y, (f16)v.z, (f16)v.w};
  out[t] = h;
  if (t == 0 && z < 4) P.bp[z * 512 + np] = P.b[z][src];
}

// ---------------------------------------------------------------------------
// B-PANEL-RESIDENT MFMA GEMM: O[m][n] = sum_k A[m][k]*B[n][k] + bias[n]
// Block = 512 thr (8 waves), owns a 64-col B panel (ALL of K=512) staged once
// into 64 KiB LDS (16 k-tiles of [64 rows x 32 k] f16, verified XOR swizzle
// slot' = q ^ ((row>>1)&3)). ONE barrier total; K-loop has no barriers and no
// B re-staging. Each wave owns 128 A-rows (8 m-tiles), 2 passes x 4 m-tiles;
// A fragments stream direct from global with 2 named prefetch sets (read
// once; same-x blocks share via same-XCD L2). Ratios per kc: 4 ds_read_b128 +
// 4 A-loads : 16 MFMA. CVT_A: A fp32 -> f16 at consume.
// ---------------------------------------------------------------------------
struct GemmF16 { const void* X[4]; const f16* W[4]; const float* Bi[4]; void* O[4]; };

template <bool CVT_A, typename OutT>
__global__ __launch_bounds__(512) void gemm_bres(GemmF16 P) {
  __shared__ f16 bls[16 * 64 * 32];   // 64 KiB: [kc][row*32 + slot]

  const int z = blockIdx.z;
  const float* __restrict__ A32 = CVT_A ? (const float*)P.X[z] : (const float*)nullptr;
  const f16*  __restrict__ A16 = CVT_A ? (const f16*)nullptr : (const f16*)P.X[z];
  const f16* __restrict__ Bg = P.W[z] + (size_t)blockIdx.y * 64 * 512;
  const float* __restrict__ Bi = P.Bi[z];
  OutT* __restrict__ O = (OutT*)P.O[z];

  const int tid = threadIdx.x;
  const int lane = tid & 63;
  const int wid = tid >> 6;

  // ---- stage whole B panel, one global_load_lds(16B) per (wave, tile) ----
  {
    const int sw  = wid & 3;            // sub-wave row group
    const int kc0 = (wid >> 2) * 8;     // waves 0-3: tiles 0-7; 4-7: tiles 8-15
    const int r = sw * 16 + (lane >> 2);       // panel row 0..63
    const int q = lane & 3;
    const int qs = q ^ ((r >> 1) & 3);         // inverse swizzle on source
    #pragma unroll
    for (int i = 0; i < 8; ++i) {
      const int kc = kc0 + i;
      const f16* src = Bg + (size_t)r * 512 + kc * 32 + qs * 8;
      __builtin_amdgcn_global_load_lds(
          (const __attribute__((address_space(1))) void*)src,
          (__attribute__((address_space(3))) void*)(bls + kc * 2048 + sw * 512),
          16, 0, 0);
    }
  }
  __syncthreads();   // drains vmcnt; the ONLY barrier

  const int g = lane >> 4, c = lane & 15;
  int boff[4];
  #pragma unroll
  for (int nt = 0; nt < 4; ++nt)
    boff[nt] = (nt * 16 + c) * 32 + ((g ^ ((c >> 1) & 3)) * 8);

  const int nbase = (int)blockIdx.y * 64;
  float bv[4];
  #pragma unroll
  for (int nt = 0; nt < 4; ++nt) bv[nt] = Bi[nbase + nt * 16 + c];

  const size_t mwave = (size_t)blockIdx.x * 1024 + (size_t)wid * 128;

  #pragma unroll
  for (int pass = 0; pass < 2; ++pass) {
    const float* pa32[4];
    const f16*  pa16[4];
    #pragma unroll
    for (int mi = 0; mi < 4; ++mi) {
      const size_t arow = mwave + pass * 64 + mi * 16 + c;
      if (CVT_A) pa32[mi] = A32 + arow * 512 + g * 8;
      else       pa16[mi] = A16 + arow * 512 + g * 8;
    }

    f32x4 acc[4][4];
    #pragma unroll
    for (int mi = 0; mi < 4; ++mi)
      #pragma unroll
      for (int nt = 0; nt < 4; ++nt) acc[mi][nt] = (f32x4){0.f, 0.f, 0.f, 0.f};

    // two named A prefetch sets (rule #20: no runtime indexing)
    float4 u0[4][2], u1[4][2];
    f16x8 h0[4], h1[4];

#define LA(SET, KC) do {                                                       \
    _Pragma("unroll")                                                          \
    for (int mi = 0; mi < 4; ++mi) {                                           \
      if (CVT_A) {                                                             \
        const float* p = pa32[mi] + (KC) * 32;                                 \
        u##SET[mi][0] = *(const float4*)p;                                     \
        u##SET[mi][1] = *(const float4*)(p + 4);                               \
      } else {                                                                 \
        h##SET[mi] = *(const f16x8*)(pa16[mi] + (KC) * 32);                    \
      }                                                                        \
    } } while (0)

    LA(0, 0);
    #pragma unroll
    for (int kc = 0; kc < 16; ++kc) {
      if (kc < 15) { if ((kc & 1) == 0) LA(1, kc + 1); else LA(0, kc + 1); }

      f16x8 bf[4];
      #pragma unroll
      for (int nt = 0; nt < 4; ++nt)
        bf[nt] = *(const f16x8*)&bls[kc * 2048 + boff[nt]];

      f16x8 af[4];
      #pragma unroll
      for (int mi = 0; mi < 4; ++mi) {
        if ((kc & 1) == 0) {
          if constexpr (CVT_A) af[mi] = cvt8(u0[mi][0], u0[mi][1]);
          else                 af[mi] = h0[mi];
        } else {
          if constexpr (CVT_A) af[mi] = cvt8(u1[mi][0], u1[mi][1]);
          else                 af[mi] = h1[mi];
        }
      }
      #pragma unroll
      for (int mi = 0; mi < 4; ++mi)
        #pragma unroll
        for (int nt = 0; nt < 4; ++nt)
          acc[mi][nt] = __builtin_amdgcn_mfma_f32_16x16x32_f16(
              af[mi], bf[nt], acc[mi][nt], 0, 0, 0);
    }
#undef LA

    // epilogue: D col = c (n), row = g*4 + r (m)  [m89-verified layout]
    #pragma unroll
    for (int mi = 0; mi < 4; ++mi) {
      const size_t rb = mwave + pass * 64 + mi * 16 + g * 4;
      #pragma unroll
      for (int nt = 0; nt < 4; ++nt)
        #pragma unroll
        for (int r = 0; r < 4; ++r)
          O[(rb + r) * 512 + nbase + nt * 16 + c] = (OutT)(acc[mi][nt][r] + bv[nt]);
    }
  }
}

// ---------------------------------------------------------------------------
// MFMA windowed attention. One WAVE per (b,h,wi,wj); 4 waves/block.
// (unchanged from round 6 -- verified correct & fast, ~71 us)
// ---------------------------------------------------------------------------
__global__ __launch_bounds__(256) void attn_kernel(
    const f16* __restrict__ cq, const f16* __restrict__ ck,
    const f16* __restrict__ vs, const f16* __restrict__ vh,
    const float* __restrict__ pe, f16* __restrict__ osc, f16* __restrict__ osh) {
  __shared__ f16 Pl[4][64][72];     // per-wave P[q][kv], stride 144B (16B mult)
  __shared__ float pesh[228];

  const int tid = threadIdx.x;
  for (int i = tid; i < 225; i += 256) pesh[i] = pe[i];
  __syncthreads();                  // only barrier (pesh shared per block)

  const int wid = tid >> 6;
  const int lane = tid & 63;
  const int g = lane >> 4;          // 0..3
  const int c = lane & 15;          // 0..15
  const int w = blockIdx.x * 4 + wid;
  const int wj = w & 7;
  const int wi = (w >> 3) & 7;
  const int h  = (w >> 6) & 15;
  const int b  = w >> 10;

  size_t taddr[4];
  #pragma unroll
  for (int i = 0; i < 4; ++i) {
    const int ty = (wi * 8 + i * 2 + (c >> 3) + 4) & 63;
    const int tx = (wj * 8 + (c & 7) + 4) & 63;
    taddr[i] = ((size_t)b * NTOK + ty * 64 + tx) * EMB + h * 32 + g * 8;
  }
  f16x8 kf[4], qf[4];
  #pragma unroll
  for (int i = 0; i < 4; ++i) {
    kf[i] = *(const f16x8*)(ck + taddr[i]);
    qf[i] = *(const f16x8*)(cq + taddr[i]);
  }

  f32x4 s[4][4];
  #pragma unroll
  for (int mt = 0; mt < 4; ++mt)
    #pragma unroll
    for (int kt = 0; kt < 4; ++kt) s[mt][kt] = (f32x4){0.f, 0.f, 0.f, 0.f};
  #pragma unroll
  for (int mt = 0; mt < 4; ++mt)
    #pragma unroll
    for (int kt = 0; kt < 4; ++kt)
      s[mt][kt] = __builtin_amdgcn_mfma_f32_16x16x32_f16(kf[mt], qf[kt],
                                                         s[mt][kt], 0, 0, 0);

  const float invs = 0.17677669529663687f;  // 1/sqrt(32)
  const bool rm = (wi == 7);
  const bool cm = (wj == 7) && (((c >> 2) & 1) != (g & 1));  // lane-constant
  #pragma unroll
  for (int mt = 0; mt < 4; ++mt)
    #pragma unroll
    for (int kt = 0; kt < 4; ++kt) {
      const bool rmask = rm && ((mt >> 1) != (kt >> 1));     // acc-uniform
      const int ry = (mt - kt) * 2 + (g >> 1) - (c >> 3) + 7;
      #pragma unroll
      for (int r = 0; r < 4; ++r) {
        const int rx = (g & 1) * 4 + r - (c & 7) + 7;
        float d = s[mt][kt][r] * invs + pesh[ry * 15 + rx];
        if (rmask || cm) d = -1e30f;
        s[mt][kt][r] = d;
      }
    }

  #pragma unroll
  for (int kt = 0; kt < 4; ++kt) {
    float m = -1e30f;
    #pragma unroll
    for (int mt = 0; mt < 4; ++mt)
      #pragma unroll
      for (int r = 0; r < 4; ++r) m = fmaxf(m, s[mt][kt][r]);
    m = fmaxf(m, __shfl_xor(m, 16));
    m = fmaxf(m, __shfl_xor(m, 32));
    float sum = 0.f;
    #pragma unroll
    for (int mt = 0; mt < 4; ++mt)
      #pragma unroll
      for (int r = 0; r < 4; ++r) {
        const float p = __expf(s[mt][kt][r] - m);
        s[mt][kt][r] = p;
        sum += p;
      }
    sum += __shfl_xor(sum, 16);
    sum += __shfl_xor(sum, 32);
    const float rs = 1.f / sum;
    #pragma unroll
    for (int mt = 0; mt < 4; ++mt)
      #pragma unroll
      for (int r = 0; r < 4; ++r) s[mt][kt][r] *= rs;
  }

  #pragma unroll
  for (int mt = 0; mt < 4; ++mt)
    #pragma unroll
    for (int kt = 0; kt < 4; ++kt) {
      f16x4 pk = {(f16)s[mt][kt][0], (f16)s[mt][kt][1],
                  (f16)s[mt][kt][2], (f16)s[mt][kt][3]};
      *(f16x4*)&Pl[wid][kt * 16 + c][mt * 16 + g * 4] = pk;
    }

  size_t vb[2];
  #pragma unroll
  for (int ks = 0; ks < 2; ++ks) {
    const int vy = (wi * 8 + ks * 4 + g + 4) & 63;
    vb[ks] = ((size_t)b * NTOK + vy * 64) * EMB + h * 32 + c;
  }
  int xo[8];
  #pragma unroll
  for (int j = 0; j < 8; ++j) xo[j] = ((wj * 8 + j + 4) & 63) * EMB;

  f16x8 vfs[2][2], vfh[2][2];   // [nt][ks]
  #pragma unroll
  for (int nt = 0; nt < 2; ++nt)
    #pragma unroll
    for (int ks = 0; ks < 2; ++ks)
      #pragma unroll
      for (int j = 0; j < 8; ++j) {
        const size_t a = vb[ks] + xo[j] + nt * 16;
        vfs[nt][ks][j] = vs[a];
        vfh[nt][ks][j] = vh[a];
      }

  f16x8 af[4][2];
  #pragma unroll
  for (int mt = 0; mt < 4; ++mt)
    #pragma unroll
    for (int ks = 0; ks < 2; ++ks)
      af[mt][ks] = *(const f16x8*)&Pl[wid][mt * 16 + c][ks * 32 + g * 8];

  size_t ob[4];
  #pragma unroll
  for (int mt = 0; mt < 4; ++mt) {
    const int np = (wi * 8 + 2 * mt + (g >> 1)) * 64 + wj * 8 + 4 * (g & 1);
    ob[mt] = ((size_t)b * NTOK + np) * EMB + h * 32 + c;
  }

  {
    f32x4 o[4][2];
    #pragma unroll
    for (int mt = 0; mt < 4; ++mt)
      #pragma unroll
      for (int nt = 0; nt < 2; ++nt) o[mt][nt] = (f32x4){0.f, 0.f, 0.f, 0.f};
    #pragma unroll
    for (int mt = 0; mt < 4; ++mt)
      #pragma unroll
      for (int nt = 0; nt < 2; ++nt)
        #pragma unroll
        for (int ks = 0; ks < 2; ++ks)
          o[mt][nt] = __builtin_amdgcn_mfma_f32_16x16x32_f16(
              af[mt][ks], vfs[nt][ks], o[mt][nt], 0, 0, 0);
    #pragma unroll
    for (int mt = 0; mt < 4; ++mt)
      #pragma unroll
      for (int nt = 0; nt < 2; ++nt)
        #pragma unroll
        for (int r = 0; r < 4; ++r)
          osc[ob[mt] + (size_t)r * EMB + nt * 16] = (f16)o[mt][nt][r];
  }
  {
    f32x4 o[4][2];
    #pragma unroll
    for (int mt = 0; mt < 4; ++mt)
      #pragma unroll
      for (int nt = 0; nt < 2; ++nt) o[mt][nt] = (f32x4){0.f, 0.f, 0.f, 0.f};
    #pragma unroll
    for (int mt = 0; mt < 4; ++mt)
      #pragma unroll
      for (int nt = 0; nt < 2; ++nt)
        #pragma unroll
        for (int ks = 0; ks < 2; ++ks)
          o[mt][nt] = __builtin_amdgcn_mfma_f32_16x16x32_f16(
              af[mt][ks], vfh[nt][ks], o[mt][nt], 0, 0, 0);
    #pragma unroll
    for (int mt = 0; mt < 4; ++mt)
      #pragma unroll
      for (int nt = 0; nt < 2; ++nt)
        #pragma unroll
        for (int r = 0; r < 4; ++r)
          osh[ob[mt] + (size_t)r * EMB + nt * 16] = (f16)o[mt][nt][r];
  }
}

// ---------------------------------------------------------------------------
extern "C" void kernel_launch(void* const* d_in, const int* in_sizes, int n_in,
                              void* d_out, int out_size, void* d_ws, size_t ws_size,
                              hipStream_t stream) {
  const float* content = (const float*)d_in[0];
  const float* style   = (const float*)d_in[1];
  const float* scalex  = (const float*)d_in[2];
  const float* shiftx  = (const float*)d_in[3];
  const float* W1  = (const float*)d_in[4];  const float* b1  = (const float*)d_in[5];
  const float* W2  = (const float*)d_in[6];  const float* b2  = (const float*)d_in[7];
  const float* Wsc = (const float*)d_in[8];  const float* bsc = (const float*)d_in[9];
  const float* Wsh = (const float*)d_in[10]; const float* bsh = (const float*)d_in[11];
  const float* Wso = (const float*)d_in[12]; const float* bso = (const float*)d_in[13];
  const float* Wsho= (const float*)d_in[14]; const float* bsho= (const float*)d_in[15];
  const float* pos = (const float*)d_in[16];
  float* out = (float*)d_out;

  // workspace: Wh(6x262144 f16) | bp(2048 f32) | Ph(4xNELEM f16) | Oh(2xNELEM f16)
  f16* Wh = (f16*)d_ws;
  float* bp = (float*)(Wh + 6 * 262144);
  f16* Ph = (f16*)(bp + 2048);
  f16* Oh = Ph + 4 * NELEM;

  // 1) convert weights (P1 rows permuted to head-major) + biases
  CvtW CW;
  CW.w[0] = W1; CW.w[1] = W2; CW.w[2] = Wsc; CW.w[3] = Wsh; CW.w[4] = Wso; CW.w[5] = Wsho;
  CW.b[0] = b1; CW.b[1] = b2; CW.b[2] = bsc; CW.b[3] = bsh;
  for (int i = 0; i < 6; ++i) CW.out[i] = Wh + (size_t)i * 262144;
  CW.bp = bp;
  hipLaunchKernelGGL(cvt_w, dim3(512, 6), dim3(128), 0, stream, CW);

  // 2) input projections: fp32 A converted at consume, f16 head-major out
  GemmF16 P1;
  P1.X[0] = content; P1.X[1] = style; P1.X[2] = scalex; P1.X[3] = shiftx;
  for (int i = 0; i < 4; ++i) {
    P1.W[i] = Wh + (size_t)i * 262144;
    P1.Bi[i] = bp + i * 512;
    P1.O[i] = Ph + (size_t)i * NELEM;
  }
  hipLaunchKernelGGL(HIP_KERNEL_NAME(gemm_bres<true, f16>),
                     dim3(M_TOT / 1024, EMB / 64, 4), dim3(512), 0, stream, P1);

  // 3) attention: 8192 window-heads, 1 wave each, 4 waves/block
  hipLaunchKernelGGL(attn_kernel, dim3(BSZ * HEADS * WN * WN / 4), dim3(256), 0,
                     stream, Ph, Ph + NELEM, Ph + 2 * NELEM, Ph + 3 * NELEM, pos,
                     Oh, Oh + NELEM);

  // 4) output projections (f16 A, fp32 out -> d_out)
  GemmF16 P2;
  P2.X[0] = Oh;          P2.W[0] = Wh + 4 * 262144; P2.Bi[0] = bso;  P2.O[0] = out;
  P2.X[1] = Oh + NELEM;  P2.W[1] = Wh + 5 * 262144; P2.Bi[1] = bsho; P2.O[1] = out + NELEM;
  P2.X[2] = P2.X[0]; P2.W[2] = P2.W[0]; P2.Bi[2] = P2.Bi[0]; P2.O[2] = P2.O[0];
  P2.X[3] = P2.X[1]; P2.W[3] = P2.W[1]; P2.Bi[3] = P2.Bi[1]; P2.O[3] = P2.O[1];
  hipLaunchKernelGGL(HIP_KERNEL_NAME(gemm_bres<false, float>),
                     dim3(M_TOT / 1024, EMB / 64, 2), dim3(512), 0, stream, P2);
}